// Round 5
// baseline (311.322 us; speedup 1.0000x reference)
//
#include <hip/hip_runtime.h>

// DeepGCN forward on MI355X.
// R4 post-mortem: mega1's fill still #1 (44us, WRITE 51MB vs 5.1MB payload):
// scattered 8B stores from all 8 XCDs dirty each line in multiple L2s ->
// multi-writeback + partial-line RMW (FETCH 24MB).
// R5: (a) row-partitioned fill/hist -- blocks with blockIdx&7==q write only
// contiguous row range q, so CSR lines + pos/deg atomic lines stay XCD-local
// (costs 8x erow re-read, sequential & cheap); (b) SpMM x8 unroll + nontemporal
// edge-stream loads to preserve z (10MB, reused) in per-XCD L2.

#define DIN 256
#define HID 128
#define NCLS 64

typedef __attribute__((ext_vector_type(8))) short bf16x8;   // 8 bf16 = 4 VGPRs
typedef __attribute__((ext_vector_type(4))) float f32x4;

static __device__ __forceinline__ float bf2f(unsigned int u) {
    return __uint_as_float(u << 16);
}
static __device__ __forceinline__ unsigned short f2bf(float f) {
    unsigned int i = __float_as_uint(f);
    unsigned int r = (i + 0x7FFFu + ((i >> 16) & 1u)) >> 16;   // RNE
    return (unsigned short)r;
}
static __device__ __forceinline__ unsigned int pack2(float a, float b) {
    return (unsigned int)f2bf(a) | ((unsigned int)f2bf(b) << 16);
}

// ---------------- CSR build ----------------

// Partitioned histogram: 624 blocks; blocks with blockIdx&7==q count only rows
// in range q -> deg atomic lines stay on one XCD. Each partition scans all E.
__global__ __launch_bounds__(256) void hist_kernel(
        const int* __restrict__ row, int* __restrict__ deg, int E, int chunk, int N) {
    const int part = blockIdx.x & 7;
    const int rp   = blockIdx.x >> 3;          // 0..77
    const int lo = part * chunk;
    const int hi = min(lo + chunk, N);
    for (int e = rp * 256 + (int)threadIdx.x; e < E; e += 78 * 256) {
        int r = row[e];
        if ((unsigned)(r - lo) < (unsigned)(hi - lo))
            atomicAdd(&deg[r], 1);
    }
}

// Hierarchical scan, tile = 1024. k1: per-tile sums.
__global__ __launch_bounds__(1024) void scan_sums_kernel(
        const int* __restrict__ deg, int* __restrict__ bsums, int n) {
    __shared__ int wsum[16];
    const int lane = threadIdx.x & 63;
    const int wid  = threadIdx.x >> 6;
    int i = blockIdx.x * 1024 + threadIdx.x;
    int v = (i < n) ? deg[i] : 0;
    #pragma unroll
    for (int d = 32; d >= 1; d >>= 1) v += __shfl_xor(v, d, 64);
    if (lane == 0) wsum[wid] = v;
    __syncthreads();
    if (threadIdx.x == 0) {
        int s = 0;
        #pragma unroll
        for (int w = 0; w < 16; ++w) s += wsum[w];
        bsums[blockIdx.x] = s;
    }
}

// k2: tile exclusive scan + block prefix from bsums; writes offs AND pos.
__global__ __launch_bounds__(1024) void scan_fix_kernel(
        const int* __restrict__ deg, const int* __restrict__ bsums,
        int* __restrict__ offs, int* __restrict__ pos, int n, int nb) {
    __shared__ int wsum[16];
    __shared__ int bpref_s;
    const int lane = threadIdx.x & 63;
    const int wid  = threadIdx.x >> 6;
    const int b = blockIdx.x;
    if (wid == 0) {
        int v = (lane < nb && lane < b) ? bsums[lane] : 0;
        #pragma unroll
        for (int d = 32; d >= 1; d >>= 1) v += __shfl_xor(v, d, 64);
        if (lane == 0) bpref_s = v;
    }
    int i = b * 1024 + (int)threadIdx.x;
    int v = (i < n) ? deg[i] : 0;
    int incl = v;
    #pragma unroll
    for (int d = 1; d < 64; d <<= 1) {
        int t = __shfl_up(incl, d, 64);
        if (lane >= d) incl += t;
    }
    if (lane == 63) wsum[wid] = incl;
    __syncthreads();
    int wpref = 0;
    #pragma unroll
    for (int w = 0; w < 16; ++w)
        if (w < wid) wpref += wsum[w];
    int excl = bpref_s + wpref + incl - v;
    if (i < n) { offs[i] = excl; pos[i] = excl; }
    if (i == n) offs[n] = excl;
}

// ---------------- weight prep ----------------
__global__ void wtrans_all_kernel(const float* __restrict__ w1, const float* __restrict__ wm,
                                  const float* __restrict__ w2,
                                  unsigned short* __restrict__ w1t, unsigned short* __restrict__ wmt,
                                  unsigned short* __restrict__ w2t, int L) {
    int idx = blockIdx.x * blockDim.x + threadIdx.x;
    int n1 = DIN * HID;
    int n2 = n1 + L * HID * HID;
    int n3 = n2 + HID * NCLS;
    if (idx < n1) {
        int n = idx / DIN, k = idx - n * DIN;
        w1t[idx] = f2bf(w1[(size_t)k * HID + n]);
    } else if (idx < n2) {
        int j = idx - n1;
        int i = j / (HID * HID), r = j - i * (HID * HID);
        int n = r / HID, k = r - n * HID;
        wmt[j] = f2bf(wm[(size_t)i * HID * HID + (size_t)k * HID + n]);
    } else if (idx < n3) {
        int j = idx - n2;
        int n = j / HID, k = j - n * HID;
        w2t[j] = f2bf(w2[(size_t)k * NCLS + n]);
    }
}

// ---------------- MEGA1: GEMM1 (x fp32->bf16 inline) || row-partitioned CSR fill ----------------
// Grid = gemmBlocks + 624. Fill blocks: partition q = blockIdx&7 handles rows
// [q*chunk,(q+1)*chunk): destination lines + pos atomics stay on XCD q.
__global__ __launch_bounds__(256) void mega1_kernel(
        const float* __restrict__ x, const unsigned short* __restrict__ w1t,
        const float* __restrict__ b1, unsigned short* __restrict__ z,
        const int* __restrict__ erow, const int* __restrict__ ecol,
        const float* __restrict__ eval, int* __restrict__ pos,
        long long* __restrict__ edges, int E, int chunk, int N, int gemmBlocks) {
    const int tid = threadIdx.x;
    if ((int)blockIdx.x >= gemmBlocks) {
        const int fb   = blockIdx.x - gemmBlocks;   // 0..623
        const int part = blockIdx.x & 7;
        const int rp   = fb >> 3;                   // 0..77 (one per part)
        const int lo = part * chunk;
        const int hi = min(lo + chunk, N);
        for (int e = rp * 256 + tid; e < E; e += 78 * 256) {
            int r = erow[e];
            if ((unsigned)(r - lo) < (unsigned)(hi - lo)) {
                int p = atomicAdd(&pos[r], 1);
                long long o = ((long long)__float_as_int(eval[e]) << 32) | (unsigned int)ecol[e];
                edges[p] = o;
            }
        }
        return;
    }
    // ---- GEMM1 tile: 64 x 128, K=256 ----
    __shared__ __align__(16) unsigned short Alds[64 * 40];
    __shared__ __align__(16) unsigned short Blds[128 * 40];
    const int bm   = blockIdx.x * 64;
    const int wave = tid >> 6;
    const int lane = tid & 63;
    const int m16  = lane & 15;
    const int quad = lane >> 4;
    const int ar = tid >> 2, ac = (tid & 3) * 8;

    f32x4 acc[8] = {};
    for (int k0 = 0; k0 < DIN; k0 += 32) {
        float4 a0 = *(const float4*)&x[(size_t)(bm + ar) * DIN + k0 + ac];
        float4 a1 = *(const float4*)&x[(size_t)(bm + ar) * DIN + k0 + ac + 4];
        uint4 av;
        av.x = pack2(a0.x, a0.y); av.y = pack2(a0.z, a0.w);
        av.z = pack2(a1.x, a1.y); av.w = pack2(a1.z, a1.w);
        *(uint4*)&Alds[ar * 40 + ac] = av;
        #pragma unroll
        for (int i = 0; i < 2; ++i) {
            int c  = tid + 256 * i;
            int br = c >> 2, bc = (c & 3) * 8;
            *(uint4*)&Blds[br * 40 + bc] = *(const uint4*)&w1t[(size_t)br * DIN + k0 + bc];
        }
        __syncthreads();
        bf16x8 af = *(const bf16x8*)&Alds[(wave * 16 + m16) * 40 + quad * 8];
        #pragma unroll
        for (int j = 0; j < 8; ++j) {
            bf16x8 bf = *(const bf16x8*)&Blds[(j * 16 + m16) * 40 + quad * 8];
            acc[j] = __builtin_amdgcn_mfma_f32_16x16x32_bf16(af, bf, acc[j], 0, 0, 0);
        }
        __syncthreads();
    }
    #pragma unroll
    for (int j = 0; j < 8; ++j) {
        int col = j * 16 + m16;
        float bb = b1[col];
        #pragma unroll
        for (int r = 0; r < 4; ++r) {
            int row = bm + wave * 16 + quad * 4 + r;
            z[(size_t)row * HID + col] = f2bf(acc[j][r] + bb);
        }
    }
}

// ---------------- MFMA bf16 GEMM (A bf16): C[N,BN]=A@Wt^T+bias ----------------
template <int BN>
__global__ __launch_bounds__(256) void gemm_mfma_kernel(
        const unsigned short* __restrict__ A, const unsigned short* __restrict__ Wt,
        const float* __restrict__ bias, unsigned short* __restrict__ C, int K) {
    constexpr int NT = BN / 16;
    __shared__ __align__(16) unsigned short Alds[64 * 40];
    __shared__ __align__(16) unsigned short Blds[BN * 40];
    const int tid  = threadIdx.x;
    const int bm   = blockIdx.x * 64;
    const int wave = tid >> 6;
    const int lane = tid & 63;
    const int m16  = lane & 15;
    const int quad = lane >> 4;
    const int ar = tid >> 2, ac = (tid & 3) * 8;

    f32x4 acc[NT] = {};
    for (int k0 = 0; k0 < K; k0 += 32) {
        uint4 av = *(const uint4*)&A[(size_t)(bm + ar) * K + k0 + ac];
        *(uint4*)&Alds[ar * 40 + ac] = av;
        #pragma unroll
        for (int i = 0; i < BN / 64; ++i) {
            int c  = tid + 256 * i;
            int br = c >> 2, bc = (c & 3) * 8;
            *(uint4*)&Blds[br * 40 + bc] = *(const uint4*)&Wt[(size_t)br * K + k0 + bc];
        }
        __syncthreads();
        bf16x8 af = *(const bf16x8*)&Alds[(wave * 16 + m16) * 40 + quad * 8];
        #pragma unroll
        for (int j = 0; j < NT; ++j) {
            bf16x8 bf = *(const bf16x8*)&Blds[(j * 16 + m16) * 40 + quad * 8];
            acc[j] = __builtin_amdgcn_mfma_f32_16x16x32_bf16(af, bf, acc[j], 0, 0, 0);
        }
        __syncthreads();
    }
    #pragma unroll
    for (int j = 0; j < NT; ++j) {
        int col = j * 16 + m16;
        float bb = bias[col];
        #pragma unroll
        for (int r = 0; r < 4; ++r) {
            int row = bm + wave * 16 + quad * 4 + r;
            C[(size_t)row * BN + col] = f2bf(acc[j][r] + bb);
        }
    }
}

// ---------------- SpMM over bf16 z, packed edges, fp32 accumulate ----------------
// One wave/row; x8 unroll (8 gathers in flight); edges streamed nontemporal.
// MODE 0: h = relu(s); hb = bf16(h)   MODE 1: h += relu(s)*dt; hb = bf16(h)
// MODE 2: out = s (fp32)
template <int D, int MODE>
__global__ __launch_bounds__(256) void spmm_kernel(
        const int* __restrict__ offs, const long long* __restrict__ edges,
        const unsigned short* __restrict__ z,
        float* __restrict__ out, unsigned short* __restrict__ hb,
        const float* __restrict__ dt_ptr, int n) {
    int r = (int)((blockIdx.x * blockDim.x + threadIdx.x) >> 6);
    int lane = threadIdx.x & 63;
    if (r >= n) return;
    r = __builtin_amdgcn_readfirstlane(r);
    const int s = offs[r], e = offs[r + 1];
    float acc0 = 0.f, acc1 = 0.f;
    int p = s;
    if (D == 128) {
        const unsigned int* z32 = (const unsigned int*)z;
        for (; p + 8 <= e; p += 8) {
            long long ev[8];
            unsigned int g[8];
            #pragma unroll
            for (int i = 0; i < 8; ++i) ev[i] = __builtin_nontemporal_load(edges + p + i);
            #pragma unroll
            for (int i = 0; i < 8; ++i)
                g[i] = z32[(size_t)(int)((unsigned int)ev[i]) * 64 + lane];
            #pragma unroll
            for (int i = 0; i < 8; ++i) {
                float v = __int_as_float((int)(ev[i] >> 32));
                acc0 = fmaf(v, bf2f(g[i] & 0xffffu), acc0);
                acc1 = fmaf(v, bf2f(g[i] >> 16), acc1);
            }
        }
        for (; p < e; ++p) {
            long long ev = __builtin_nontemporal_load(edges + p);
            float v = __int_as_float((int)(ev >> 32));
            unsigned int g = z32[(size_t)(int)((unsigned int)ev) * 64 + lane];
            acc0 = fmaf(v, bf2f(g & 0xffffu), acc0);
            acc1 = fmaf(v, bf2f(g >> 16), acc1);
        }
        float2* op = (float2*)&out[(size_t)r * 128 + 2 * lane];
        float f0, f1;
        if (MODE == 0) {
            f0 = fmaxf(acc0, 0.f); f1 = fmaxf(acc1, 0.f);
            float2 o; o.x = f0; o.y = f1; *op = o;
        } else if (MODE == 1) {
            float dt = *dt_ptr;
            float2 cur = *op;
            f0 = cur.x + fmaxf(acc0, 0.f) * dt;
            f1 = cur.y + fmaxf(acc1, 0.f) * dt;
            float2 o; o.x = f0; o.y = f1; *op = o;
        } else {
            float2 o; o.x = acc0; o.y = acc1; *op = o;
            return;
        }
        __builtin_nontemporal_store(pack2(f0, f1), (unsigned int*)hb + (size_t)r * 64 + lane);
    } else {  // D == 64 (final layer, MODE 2)
        for (; p + 8 <= e; p += 8) {
            long long ev[8];
            unsigned int g[8];
            #pragma unroll
            for (int i = 0; i < 8; ++i) ev[i] = __builtin_nontemporal_load(edges + p + i);
            #pragma unroll
            for (int i = 0; i < 8; ++i)
                g[i] = z[(size_t)(int)((unsigned int)ev[i]) * 64 + lane];
            #pragma unroll
            for (int i = 0; i < 8; ++i)
                acc0 = fmaf(__int_as_float((int)(ev[i] >> 32)), bf2f(g[i]), acc0);
        }
        for (; p < e; ++p) {
            long long ev = __builtin_nontemporal_load(edges + p);
            acc0 = fmaf(__int_as_float((int)(ev >> 32)),
                        bf2f((unsigned int)z[(size_t)(int)((unsigned int)ev) * 64 + lane]), acc0);
        }
        out[(size_t)r * 64 + lane] = acc0;
    }
}

extern "C" void kernel_launch(void* const* d_in, const int* in_sizes, int n_in,
                              void* d_out, int out_size, void* d_ws, size_t ws_size,
                              hipStream_t stream) {
    const float* x    = (const float*)d_in[0];
    const int*   erow = (const int*)d_in[1];
    const int*   ecol = (const int*)d_in[2];
    const float* eval = (const float*)d_in[3];
    const float* w1   = (const float*)d_in[4];
    const float* b1   = (const float*)d_in[5];
    const float* wm   = (const float*)d_in[6];
    const float* bmp  = (const float*)d_in[7];
    const float* w2   = (const float*)d_in[8];
    const float* b2   = (const float*)d_in[9];
    const float* dt   = (const float*)d_in[10];

    const int N = in_sizes[0] / DIN;       // 40000
    const int E = in_sizes[1];             // 640000
    const int L = in_sizes[7] / HID;       // 2
    const int chunk = (N + 7) / 8;

    float* outp = (float*)d_out;

    char* ws = (char*)d_ws;
    auto carve = [&](size_t bytes) -> char* {
        char* p = ws;
        ws += (bytes + 255) & ~(size_t)255;
        return p;
    };
    int*            deg   = (int*)carve((size_t)N * 4);
    int*            bsums = (int*)carve(64 * 4);
    int*            offs  = (int*)carve((size_t)(N + 1) * 4);
    int*            pos   = (int*)carve((size_t)N * 4);
    long long*      edges = (long long*)carve((size_t)E * 8);
    unsigned short* z     = (unsigned short*)carve((size_t)N * HID * 2);
    float*          h     = (float*)carve((size_t)N * HID * 4);
    unsigned short* hb    = (unsigned short*)carve((size_t)N * HID * 2);
    unsigned short* w1t   = (unsigned short*)carve((size_t)HID * DIN * 2);
    unsigned short* wmt   = (unsigned short*)carve((size_t)L * HID * HID * 2);
    unsigned short* w2t   = (unsigned short*)carve((size_t)NCLS * HID * 2);

    const int ntiles = (N + 1024) / 1024;  // covers i == n
    const int wtotal = DIN * HID + L * HID * HID + HID * NCLS;

    // --- independent prep ---
    wtrans_all_kernel<<<(wtotal + 255) / 256, 256, 0, stream>>>(w1, wm, w2, w1t, wmt, w2t, L);
    hipMemsetAsync(deg, 0, (size_t)N * 4, stream);
    hist_kernel<<<624, 256, 0, stream>>>(erow, deg, E, chunk, N);
    scan_sums_kernel<<<ntiles, 1024, 0, stream>>>(deg, bsums, N);
    scan_fix_kernel<<<ntiles, 1024, 0, stream>>>(deg, bsums, offs, pos, N, ntiles);

    const int gemm_blocks = N / 64;   // 625 exact
    const int spmm_blocks = (N + 3) / 4;

    // --- GEMM1 || CSR-fill (624 fill blocks, 78 per XCD partition) ---
    mega1_kernel<<<gemm_blocks + 624, 256, 0, stream>>>(
        x, w1t, b1, z, erow, ecol, eval, pos, edges, E, chunk, N, gemm_blocks);
    spmm_kernel<HID, 0><<<spmm_blocks, 256, 0, stream>>>(offs, edges, z, h, hb, nullptr, N);

    // --- middle residual layers ---
    for (int i = 0; i < L; ++i) {
        gemm_mfma_kernel<HID><<<gemm_blocks, 256, 0, stream>>>(
            hb, wmt + (size_t)i * HID * HID, bmp + (size_t)i * HID, z, HID);
        spmm_kernel<HID, 1><<<spmm_blocks, 256, 0, stream>>>(offs, edges, z, h, hb, dt, N);
    }

    // --- output layer ---
    gemm_mfma_kernel<NCLS><<<gemm_blocks, 256, 0, stream>>>(hb, w2t, b2, z, HID);
    spmm_kernel<NCLS, 2><<<spmm_blocks, 256, 0, stream>>>(offs, edges, z, outp, nullptr, nullptr, N);
}